// Round 10
// baseline (17494.939 us; speedup 1.0000x reference)
//
#include <hip/hip_runtime.h>
#include <hip/hip_bf16.h>

#define NLAYER 6
#define DMODEL 512
#define FFDIM 2048
#define BATCH 16
#define SEQ 2048
#define MROWS (BATCH*SEQ)   // 32768

typedef __hip_bfloat16 bf16;
typedef __attribute__((ext_vector_type(4))) float f32x4;
typedef __attribute__((ext_vector_type(8))) short s16x8;

__device__ __forceinline__ float b2f(short s) {
  unsigned u = ((unsigned)(unsigned short)s) << 16;
  return __builtin_bit_cast(float, u);
}
__device__ __forceinline__ short f2b(float f) {
  bf16 t = __float2bfloat16(f);
  return __builtin_bit_cast(short, t);
}

__device__ __forceinline__ void gload_lds16(const void* g, void* l) {
  __builtin_amdgcn_global_load_lds(
      (const __attribute__((address_space(1))) void*)g,
      (__attribute__((address_space(3))) void*)l, 16, 0, 0);
}

// ---------------- setup kernels ----------------
__global__ void x_init_k(const float* __restrict__ in, bf16* __restrict__ xb, size_t n4) {
  for (size_t i = (size_t)blockIdx.x * blockDim.x + threadIdx.x; i < n4;
       i += (size_t)gridDim.x * blockDim.x) {
    f32x4 v = *(const f32x4*)(in + i * 4);
    bf16* o = xb + i * 4;
    o[0] = __float2bfloat16(v[0]); o[1] = __float2bfloat16(v[1]);
    o[2] = __float2bfloat16(v[2]); o[3] = __float2bfloat16(v[3]);
  }
}

// merged per-layer weight repack (one launch): 21504 blocks x 256
#define SEG 262144
__global__ void repack_layer_k(const float* __restrict__ wqkv, const float* __restrict__ wout,
                               const float* __restrict__ wgate, const float* __restrict__ wff1,
                               const float* __restrict__ wff2,
                               bf16* __restrict__ q, bf16* __restrict__ o, bf16* __restrict__ g,
                               bf16* __restrict__ f1, bf16* __restrict__ f2) {
  int idx = blockIdx.x * 256 + threadIdx.x;
  if (idx < 9 * SEG) {                   // w_qkv [3][512][512][3] (j,o,i,t) -> [t][j][o][i]
    int ii = idx & 511; int r = idx >> 9;
    int oo = r & 511; r >>= 9;
    int j = r % 3, t = r / 3;
    q[idx] = __float2bfloat16(wqkv[(((size_t)j * 512 + oo) * 512 + ii) * 3 + t]);
  } else if (idx < 12 * SEG) {           // w_out [512][512][3] (o,i,t) -> [t][o][i]
    int k = idx - 9 * SEG;
    int ii = k & 511; int r = k >> 9;
    int oo = r & 511; int t = r >> 9;
    o[k] = __float2bfloat16(wout[((size_t)oo * 512 + ii) * 3 + t]);
  } else if (idx < 13 * SEG) {
    int k = idx - 12 * SEG;
    g[k] = __float2bfloat16(wgate[k]);
  } else if (idx < 17 * SEG) {
    int k = idx - 13 * SEG;
    f1[k] = __float2bfloat16(wff1[k]);
  } else {
    int k = idx - 17 * SEG;
    f2[k] = __float2bfloat16(wff2[k]);
  }
}

// ---------------- GEMM: C[M,N] = sum_t A_shift(t)[M,K] * W_t[N,K] ----------------
// BM=256, BN=256, BK=64, 8 waves (2M x 4N), 16x16x32 MFMA, 3 fine phases/K-tile.
// SINGLE 64KB LDS buffer -> 2 blocks/CU (4 waves/SIMD): independent blocks'
// barriers are uncorrelated, so one block's MFMA fills the other's drain stalls.
// In-place staging is safe because each pass-region is read in exactly one
// phase and each wave's ds_reads are consumed (lgkmcnt) before its barrier;
// stages for tile t+1 are issued after the barrier ending the region's phase.
// Ledger (per-thread queue, verified): prologue a0,b0,b1,a1 of tile 0;
// P0 vmcnt(t==0?4:2) then stage a1(t); P1 vmcnt(2) then stage a0,b0(t+1);
// P2 vmcnt(pre?4:0) then stage b1(t+1). Uniform 2-phase issue->consume depth.
enum { E_SIG = 0, E_BIAS = 1, E_OUT = 2, E_RELU = 3, E_FF2 = 4 };

#define ABUF 16384   // 256*64 bf16 elements (A region)
#define BUFE 32768   // A + B regions (single buffer, 64KB)

template<int TAPS, int EPI, int KK>
__global__ __launch_bounds__(512, 4)
void gemm_k(const bf16* __restrict__ A, const bf16* __restrict__ W,
            const float* __restrict__ bias,
            bf16* __restrict__ Cb,
            const bf16* __restrict__ gate, const int* __restrict__ mask,
            const bf16* __restrict__ xres, const bf16* __restrict__ zbuf,
            int M, int N)
{
  constexpr int KT = KK / 64;        // K-tiles per tap
  constexpr int NT = TAPS * KT;      // virtual K-tiles
  __shared__ bf16 lds[BUFE];         // 65536 B -> 2 blocks/CU

  const int tid  = threadIdx.x;
  const int lane = tid & 63;
  const int w    = tid >> 6;         // 0..7
  const int wr   = w >> 2;           // 0..1 (M)
  const int wc   = w & 3;            // 0..3 (N)
  const int frow = lane & 15;
  const int kq   = lane >> 4;        // 0..3

  // T1: bijective XCD swizzle (nwg % 8 == 0 for all instantiations)
  const int nwg = gridDim.x * gridDim.y;
  const int wg  = blockIdx.y * gridDim.x + blockIdx.x;
  const int q8  = nwg >> 3;
  const int swz = (wg & 7) * q8 + (wg >> 3);
  const int row0 = (swz / gridDim.x) * 256;
  const int n0   = (swz % gridDim.x) * 256;

  // ---- precomputed staging state ----
  const int gA   = tid & 7;
  const bf16* aptr[4];
  int oobt[4];                        // tap index that must read zbuf (3 = none)
#pragma unroll
  for (int i = 0; i < 4; ++i) {
    int row  = i * 64 + (tid >> 3);
    int grow = row0 + row;
    int gswA = (gA ^ (row & 7)) * 8;
    if (TAPS == 3) {
      int l = grow & (SEQ - 1);
      oobt[i] = (l == 0) ? 0 : ((l == SEQ - 1) ? 2 : 3);
      aptr[i] = A + (size_t)(grow - 1) * KK + gswA;   // shift = -1 start
    } else {
      oobt[i] = 3;
      aptr[i] = A + (size_t)grow * KK + gswA;
    }
  }
  const int uB = tid >> 3;
  const bf16* bptr[4];
  int dstB[4];
#pragma unroll
  for (int j = 0; j < 4; ++j) {
    int row = (j >> 1) * 128 + (j & 1) * 32 + (uB & 31) + (uB >> 5) * 64;
    int gsw = (gA ^ (row & 7)) * 8;
    bptr[j] = W + (size_t)(n0 + row) * KK + gsw;
    dstB[j] = ABUF + row * 64 + gA * 8;
  }
  const size_t tapSkipB = (size_t)(N - 1) * KK;   // jump between taps for B

  auto stageA = [&](int v, int i) {
    const bf16* s = aptr[i] + (size_t)v * 64;
    if (TAPS == 3) {
      int tap = v >> 3;
      if (tap == oobt[i]) s = zbuf;
    }
    gload_lds16(s, lds + i * 4096 + tid * 8);
  };
  auto stageB = [&](int v, int j) {
    const bf16* s = bptr[j] + (size_t)v * 64;
    if (TAPS == 3) s += (size_t)(v >> 3) * tapSkipB;
    gload_lds16(s, lds + dstB[j]);
  };

  f32x4 acc[8][4] = {};

  // prologue: tile 0, EXACT order a0(A0,A2), b0(B0,B2), b1(B1,B3), a1(A1,A3)
  stageA(0, 0); stageA(0, 2); stageB(0, 0); stageB(0, 2);
  stageB(0, 1); stageB(0, 3); stageA(0, 1); stageA(0, 3);

#pragma unroll 1
  for (int t = 0; t < NT; ++t) {
    const bf16* Ab = lds;
    const bf16* Bb = lds + ABUF;
    const bool pre = (t + 1 < NT);

    auto ldA = [&](int mi, int ks) -> s16x8 {   // mi 0..7
      int row = wr * 128 + mi * 16 + frow;
      int kg  = ks * 4 + kq;
      return *(const s16x8*)&Ab[row * 64 + ((kg ^ (row & 7)) * 8)];
    };
    auto ldB = [&](int nj, int ks) -> s16x8 {   // nj 0..3
      int row = wc * 64 + nj * 16 + frow;
      int kg  = ks * 4 + kq;
      return *(const s16x8*)&Bb[row * 64 + ((kg ^ (row & 7)) * 8)];
    };

    s16x8 a0[4][2], a1[4][2], b0[2][2], b1[2][2];

    // ---- phase 0: reads A{0,2}+B{0,2} regions of t ----
    if (t == 0) asm volatile("s_waitcnt vmcnt(4)" ::: "memory");
    else        asm volatile("s_waitcnt vmcnt(2)" ::: "memory");
    __builtin_amdgcn_s_barrier();
    asm volatile("" ::: "memory");
    if (t > 0) { stageA(t, 1); stageA(t, 3); }   // a1(t): region freed at P2 of t-1
#pragma unroll
    for (int mi = 0; mi < 4; ++mi)
#pragma unroll
      for (int ks = 0; ks < 2; ++ks) a0[mi][ks] = ldA(mi, ks);
#pragma unroll
    for (int nj = 0; nj < 2; ++nj)
#pragma unroll
      for (int ks = 0; ks < 2; ++ks) b0[nj][ks] = ldB(nj, ks);
    __builtin_amdgcn_s_setprio(1);
#pragma unroll
    for (int mi = 0; mi < 4; ++mi)
#pragma unroll
      for (int nj = 0; nj < 2; ++nj) {
        acc[mi][nj] = __builtin_amdgcn_mfma_f32_16x16x32_bf16(a0[mi][0], b0[nj][0], acc[mi][nj], 0, 0, 0);
        acc[mi][nj] = __builtin_amdgcn_mfma_f32_16x16x32_bf16(a0[mi][1], b0[nj][1], acc[mi][nj], 0, 0, 0);
      }
    __builtin_amdgcn_s_setprio(0);

    // ---- phase 1: reads B{1,3} region of t ----
    asm volatile("s_waitcnt vmcnt(2)" ::: "memory");
    __builtin_amdgcn_s_barrier();
    asm volatile("" ::: "memory");
    if (pre) { stageA(t + 1, 0); stageA(t + 1, 2); stageB(t + 1, 0); stageB(t + 1, 2); }
#pragma unroll
    for (int nj = 0; nj < 2; ++nj)
#pragma unroll
      for (int ks = 0; ks < 2; ++ks) b1[nj][ks] = ldB(2 + nj, ks);
    __builtin_amdgcn_s_setprio(1);
#pragma unroll
    for (int mi = 0; mi < 4; ++mi)
#pragma unroll
      for (int nj = 0; nj < 2; ++nj) {
        acc[mi][2 + nj] = __builtin_amdgcn_mfma_f32_16x16x32_bf16(a0[mi][0], b1[nj][0], acc[mi][2 + nj], 0, 0, 0);
        acc[mi][2 + nj] = __builtin_amdgcn_mfma_f32_16x16x32_bf16(a0[mi][1], b1[nj][1], acc[mi][2 + nj], 0, 0, 0);
      }
    __builtin_amdgcn_s_setprio(0);

    // ---- phase 2: reads A{1,3} region of t ----
    if (pre) asm volatile("s_waitcnt vmcnt(4)" ::: "memory");
    else     asm volatile("s_waitcnt vmcnt(0)" ::: "memory");
    __builtin_amdgcn_s_barrier();
    asm volatile("" ::: "memory");
    if (pre) { stageB(t + 1, 1); stageB(t + 1, 3); }
#pragma unroll
    for (int mi = 0; mi < 4; ++mi)
#pragma unroll
      for (int ks = 0; ks < 2; ++ks) a1[mi][ks] = ldA(4 + mi, ks);
    __builtin_amdgcn_s_setprio(1);
#pragma unroll
    for (int mi = 0; mi < 4; ++mi)
#pragma unroll
      for (int nj = 0; nj < 2; ++nj) {
        acc[4 + mi][nj] = __builtin_amdgcn_mfma_f32_16x16x32_bf16(a1[mi][0], b0[nj][0], acc[4 + mi][nj], 0, 0, 0);
        acc[4 + mi][nj] = __builtin_amdgcn_mfma_f32_16x16x32_bf16(a1[mi][1], b0[nj][1], acc[4 + mi][nj], 0, 0, 0);
      }
#pragma unroll
    for (int mi = 0; mi < 4; ++mi)
#pragma unroll
      for (int nj = 0; nj < 2; ++nj) {
        acc[4 + mi][2 + nj] = __builtin_amdgcn_mfma_f32_16x16x32_bf16(a1[mi][0], b1[nj][0], acc[4 + mi][2 + nj], 0, 0, 0);
        acc[4 + mi][2 + nj] = __builtin_amdgcn_mfma_f32_16x16x32_bf16(a1[mi][1], b1[nj][1], acc[4 + mi][2 + nj], 0, 0, 0);
      }
    __builtin_amdgcn_s_setprio(0);
  }

  // epilogue: C/D layout col=lane&15, row=(lane>>4)*4+j (m89-verified)
#pragma unroll
  for (int mi = 0; mi < 8; ++mi) {
    int rowb = row0 + wr * 128 + mi * 16 + kq * 4;
#pragma unroll
    for (int nj = 0; nj < 4; ++nj) {
      int col = n0 + wc * 64 + nj * 16 + frow;
      float bval = bias[col];
#pragma unroll
      for (int j = 0; j < 4; ++j) {
        int rr = rowb + j;
        float v = acc[mi][nj][j] + bval;
        size_t idx = (size_t)rr * N + col;
        if (EPI == E_SIG) {
          Cb[idx] = __float2bfloat16(1.f / (1.f + __expf(-v)));
        } else if (EPI == E_BIAS) {
          Cb[idx] = __float2bfloat16(v);
        } else if (EPI == E_RELU) {
          Cb[idx] = __float2bfloat16(fmaxf(v, 0.f));
        } else if (EPI == E_OUT) {
          float gf = __bfloat162float(gate[idx]);
          float mf = (float)mask[rr];
          float rv = __bfloat162float(xres[idx]);
          Cb[idx] = __float2bfloat16(rv + v * gf * mf);
        } else if (EPI == E_FF2) {
          float mf = (float)mask[rr];
          float rv = __bfloat162float(xres[idx]);
          Cb[idx] = __float2bfloat16(rv + v * mf);
        }
      }
    }
  }
}

// ---------------- column max over L (two stage) ----------------
__global__ void colmax_partial_k(const bf16* __restrict__ k, const bf16* __restrict__ v,
                                 float* __restrict__ pk, float* __restrict__ pv) {
  int b  = blockIdx.x >> 1;
  int d  = ((blockIdx.x & 1) << 8) + threadIdx.x;
  int lc = blockIdx.y;
  const int CH = SEQ / 16;
  size_t base = ((size_t)b * SEQ + (size_t)lc * CH) * 1536 + d;
  float mk = -1e30f, mv = -1e30f;
  for (int l = 0; l < CH; ++l) {
    mk = fmaxf(mk, __bfloat162float(k[base]));
    mv = fmaxf(mv, __bfloat162float(v[base]));
    base += 1536;
  }
  size_t pidx = ((size_t)lc * BATCH + b) * DMODEL + d;
  pk[pidx] = mk; pv[pidx] = mv;
}

__global__ void colmax_final_k(const float* __restrict__ pk, const float* __restrict__ pv,
                               float* __restrict__ kg, float* __restrict__ vg) {
  int b = blockIdx.x >> 1;
  int d = ((blockIdx.x & 1) << 8) + threadIdx.x;
  float mk = -1e30f, mv = -1e30f;
  for (int lc = 0; lc < 16; ++lc) {
    size_t pidx = ((size_t)lc * BATCH + b) * DMODEL + d;
    mk = fmaxf(mk, pk[pidx]);
    mv = fmaxf(mv, pv[pidx]);
  }
  kg[(size_t)b * DMODEL + d] = mk;
  vg[(size_t)b * DMODEL + d] = mv;
}

// ---------------- 2-way softmax attention (wave per token, 16B/lane) --------
__global__ void attn_k(const bf16* __restrict__ qkv, const float* __restrict__ kg,
                       const float* __restrict__ vg, bf16* __restrict__ o) {
  int wid = threadIdx.x >> 6, lane = threadIdx.x & 63;
  int m = blockIdx.x * 4 + wid;
  int b = m >> 11;   // SEQ = 2048
  size_t base3 = (size_t)m * 1536 + lane * 8;
  const float scale = 0.04419417382415922f;  // 1/sqrt(512)
  s16x8 qv = *(const s16x8*)(qkv + base3);
  s16x8 kv = *(const s16x8*)(qkv + base3 + 512);
  s16x8 vv = *(const s16x8*)(qkv + base3 + 1024);
  size_t gbase = ((size_t)b << 9) + lane * 8;
  f32x4 kg0 = *(const f32x4*)(kg + gbase), kg1 = *(const f32x4*)(kg + gbase + 4);
  f32x4 vg0 = *(const f32x4*)(vg + gbase), vg1 = *(const f32x4*)(vg + gbase + 4);
  float qf[8], kf[8], vf[8], kgf[8], vgf[8];
#pragma unroll
  for (int j = 0; j < 8; ++j) {
    qf[j] = b2f(qv[j]);
    kf[j] = b2f(kv[j]);
    vf[j] = b2f(vv[j]);
    kgf[j] = (j < 4) ? kg0[j] : kg1[j - 4];
    vgf[j] = (j < 4) ? vg0[j] : vg1[j - 4];
  }
  float sl = 0.f, sg = 0.f;
#pragma unroll
  for (int j = 0; j < 8; ++j) { sl += qf[j] * kf[j]; sg += qf[j] * kgf[j]; }
  // segmented reduce over the 8-lane head group (head = lane>>3)
#pragma unroll
  for (int off = 4; off; off >>= 1) {
    sl += __shfl_xor(sl, off);
    sg += __shfl_xor(sg, off);
  }
  sl *= scale; sg *= scale;
  float mx = fmaxf(sl, sg);
  float e0 = __expf(sl - mx), e1 = __expf(sg - mx);
  float inv = 1.f / (e0 + e1);
  s16x8 ov;
#pragma unroll
  for (int j = 0; j < 8; ++j)
    ov[j] = f2b((e0 * vf[j] + e1 * vgf[j]) * inv);
  *(s16x8*)(o + (size_t)m * DMODEL + lane * 8) = ov;
}

// ---------------- residual'd input -> LayerNorm (wave per row) ----------------
template<bool FINAL>
__global__ void ln_k(const bf16* __restrict__ r, const float* __restrict__ g,
                     const float* __restrict__ b, bf16* __restrict__ xb,
                     float* __restrict__ xo) {
  int wid = threadIdx.x >> 6, lane = threadIdx.x & 63;
  int row = blockIdx.x * 4 + wid;
  size_t base = (size_t)row * DMODEL + lane * 8;
  s16x8 rv = *(const s16x8*)(r + base);
  float f[8];
  float s = 0.f, ss = 0.f;
#pragma unroll
  for (int j = 0; j < 8; ++j) {
    f[j] = b2f(rv[j]);
    s += f[j]; ss += f[j] * f[j];
  }
#pragma unroll
  for (int off = 32; off; off >>= 1) {
    s  += __shfl_xor(s, off);
    ss += __shfl_xor(ss, off);
  }
  float mean = s * (1.f / (float)DMODEL);
  float var  = ss * (1.f / (float)DMODEL) - mean * mean;
  float inv  = rsqrtf(var + 1e-5f);
  int c = lane * 8;
  f32x4 g0 = *(const f32x4*)(g + c), g1 = *(const f32x4*)(g + c + 4);
  f32x4 b0 = *(const f32x4*)(b + c), b1 = *(const f32x4*)(b + c + 4);
  float y[8];
#pragma unroll
  for (int j = 0; j < 8; ++j) {
    float gj = (j < 4) ? g0[j] : g1[j - 4];
    float bj = (j < 4) ? b0[j] : b1[j - 4];
    y[j] = (f[j] - mean) * inv * gj + bj;
  }
  s16x8 yb;
#pragma unroll
  for (int j = 0; j < 8; ++j) yb[j] = f2b(y[j]);
  *(s16x8*)(xb + base) = yb;
  if (FINAL) {
    f32x4 o0, o1;
#pragma unroll
    for (int j = 0; j < 4; ++j) { o0[j] = y[j]; o1[j] = y[4 + j]; }
    *(f32x4*)(xo + base) = o0;
    *(f32x4*)(xo + base + 4) = o1;
  }
}

// ---------------- launch ----------------
extern "C" void kernel_launch(void* const* d_in, const int* in_sizes, int n_in,
                              void* d_out, int out_size, void* d_ws, size_t ws_size,
                              hipStream_t stream) {
  (void)in_sizes; (void)n_in; (void)out_size;
  const float* x      = (const float*)d_in[0];
  const int*   xmask  = (const int*)d_in[1];
  const float* w_qkv  = (const float*)d_in[2];
  const float* b_qkv  = (const float*)d_in[3];
  const float* w_gate = (const float*)d_in[4];
  const float* b_gate = (const float*)d_in[5];
  const float* w_out  = (const float*)d_in[6];
  const float* b_out  = (const float*)d_in[7];
  const float* ln1_g  = (const float*)d_in[8];
  const float* ln1_b  = (const float*)d_in[9];
  const float* w_ff1  = (const float*)d_in[10];
  const float* b_ff1  = (const float*)d_in[11];
  const float* w_ff2  = (const float*)d_in[12];
  const float* b_ff2  = (const float*)d_in[13];
  const float* ln2_g  = (const float*)d_in[14];
  const float* ln2_b  = (const float*)d_in[15];
  float* xo = (float*)d_out;

  char* ws = (char*)d_ws;
  size_t off = 0;
  auto alloc = [&](size_t bytes) {
    char* p = ws + off;
    off += (bytes + 255) & ~(size_t)255;
    return p;
  };
  // xb: bf16 copy of current x (always live)
  bf16* xb = (bf16*)alloc((size_t)MROWS * DMODEL * 2);
  // R2 shared region:
  //  attn phase: [qkvb 100.7MB | gateb 33.5MB]
  //  post-attn:  resb (bf16 residual, 33.5MB) overlays dead qkvb[0..]
  //  FFN phase:  hb (134.2MB) overlays everything (resb+gateb dead by then)
  char* R2 = alloc((size_t)MROWS * FFDIM * 2);              // 134,217,728 B
  bf16* qkvb  = (bf16*)R2;
  bf16* gateb = (bf16*)(R2 + (size_t)MROWS * 1536 * 2);
  bf16* resb  = (bf16*)R2;                                  // E_OUT out, ln1 in
  bf16* hb    = (bf16*)R2;                                  // FFN hidden
  bf16* ob    = (bf16*)alloc((size_t)MROWS * DMODEL * 2);   // attn out; later E_FF2 out
  float* kg   = (float*)alloc((size_t)BATCH * DMODEL * 4);
  float* vg   = (float*)alloc((size_t)BATCH * DMODEL * 4);
  float* pk   = (float*)alloc((size_t)16 * BATCH * DMODEL * 4);
  float* pv   = (float*)alloc((size_t)16 * BATCH * DMODEL * 4);
  bf16* zbuf  = (bf16*)alloc(256);
  // per-layer repacked weights (overwritten each layer)
  bf16* wq  = (bf16*)alloc((size_t)9 * DMODEL * DMODEL * 2);
  bf16* wg  = (bf16*)alloc((size_t)DMODEL * DMODEL * 2);
  bf16* wo  = (bf16*)alloc((size_t)3 * DMODEL * DMODEL * 2);
  bf16* wf1 = (bf16*)alloc((size_t)FFDIM * DMODEL * 2);
  bf16* wf2 = (bf16*)alloc((size_t)DMODEL * FFDIM * 2);

  // tripwire: if ws is too small, do nothing -> clean absmax fail (not a crash)
  if (off > ws_size) return;

  hipMemsetAsync(zbuf, 0, 256, stream);
  x_init_k<<<2048, 256, 0, stream>>>(x, xb, (size_t)MROWS * DMODEL / 4);

  dim3 gN512(512 / 256, MROWS / 256);    // (2, 128)  -> 256 blocks
  dim3 gN1536(1536 / 256, MROWS / 256);  // (6, 128)  -> 768 blocks
  dim3 gN2048(2048 / 256, MROWS / 256);  // (8, 128)  -> 1024 blocks

  for (int i = 0; i < NLAYER; ++i) {
    repack_layer_k<<<21 * SEG / 256, 256, 0, stream>>>(
        w_qkv + (size_t)i * 3 * DMODEL * DMODEL * 3,
        w_out + (size_t)i * DMODEL * DMODEL * 3,
        w_gate + (size_t)i * DMODEL * DMODEL,
        w_ff1 + (size_t)i * FFDIM * DMODEL,
        w_ff2 + (size_t)i * DMODEL * FFDIM,
        wq, wo, wg, wf1, wf2);

    // gate = sigmoid(x @ w_gate^T + b_gate)
    gemm_k<1, E_SIG, 512><<<gN512, 512, 0, stream>>>(
        xb, wg, b_gate + (size_t)i * DMODEL, gateb,
        nullptr, nullptr, nullptr, zbuf, MROWS, DMODEL);
    // qkv = conv1d3(x) fused over q/k/v, N = 1536
    gemm_k<3, E_BIAS, 512><<<gN1536, 512, 0, stream>>>(
        xb, wq, b_qkv + (size_t)i * 3 * DMODEL, qkvb,
        nullptr, nullptr, nullptr, zbuf, MROWS, 1536);
    // k_g, v_g global max over L
    colmax_partial_k<<<dim3(32, 16), 256, 0, stream>>>(qkvb + 512, qkvb + 1024, pk, pv);
    colmax_final_k<<<32, 256, 0, stream>>>(pk, pv, kg, vg);
    // 2-way softmax attention
    attn_k<<<MROWS / 4, 256, 0, stream>>>(qkvb, kg, vg, ob);
    // resb = x + conv1d3(o) * gate * mask   (bf16 residual)
    gemm_k<3, E_OUT, 512><<<gN512, 512, 0, stream>>>(
        ob, wo, b_out + (size_t)i * DMODEL, resb,
        gateb, xmask, xb, zbuf, MROWS, DMODEL);
    // x = LN(resb)
    ln_k<false><<<MROWS / 4, 256, 0, stream>>>(resb, ln1_g + (size_t)i * DMODEL,
                                               ln1_b + (size_t)i * DMODEL, xb, nullptr);
    // h = relu(x @ w_ff1^T + b_ff1)
    gemm_k<1, E_RELU, 512><<<gN2048, 512, 0, stream>>>(
        xb, wf1, b_ff1 + (size_t)i * FFDIM, hb,
        nullptr, nullptr, nullptr, zbuf, MROWS, FFDIM);
    // ob = x + (h @ w_ff2^T + b_ff2) * mask   (bf16 residual)
    gemm_k<1, E_FF2, 2048><<<gN512, 512, 0, stream>>>(
        hb, wf2, b_ff2 + (size_t)i * DMODEL, ob,
        nullptr, xmask, xb, zbuf, MROWS, DMODEL);
    // x = LN(ob); final layer also writes f32 output
    if (i == NLAYER - 1)
      ln_k<true><<<MROWS / 4, 256, 0, stream>>>(ob, ln2_g + (size_t)i * DMODEL,
                                                ln2_b + (size_t)i * DMODEL, xb, xo);
    else
      ln_k<false><<<MROWS / 4, 256, 0, stream>>>(ob, ln2_g + (size_t)i * DMODEL,
                                                 ln2_b + (size_t)i * DMODEL, xb, nullptr);
  }
}

// Round 11
// 2581.123 us; speedup vs baseline: 6.7780x; 6.7780x over previous
//
#include <hip/hip_runtime.h>
#include <hip/hip_bf16.h>

#define NLAYER 6
#define DMODEL 512
#define FFDIM 2048
#define BATCH 16
#define SEQ 2048
#define MROWS (BATCH*SEQ)   // 32768

typedef __hip_bfloat16 bf16;
typedef __attribute__((ext_vector_type(4))) float f32x4;
typedef __attribute__((ext_vector_type(8))) short s16x8;

__device__ __forceinline__ float b2f(short s) {
  unsigned u = ((unsigned)(unsigned short)s) << 16;
  return __builtin_bit_cast(float, u);
}
__device__ __forceinline__ short f2b(float f) {
  bf16 t = __float2bfloat16(f);
  return __builtin_bit_cast(short, t);
}

__device__ __forceinline__ void gload_lds16(const void* g, void* l) {
  __builtin_amdgcn_global_load_lds(
      (const __attribute__((address_space(1))) void*)g,
      (__attribute__((address_space(3))) void*)l, 16, 0, 0);
}

// ---------------- setup kernels ----------------
__global__ void x_init_k(const float* __restrict__ in, bf16* __restrict__ xb, size_t n4) {
  for (size_t i = (size_t)blockIdx.x * blockDim.x + threadIdx.x; i < n4;
       i += (size_t)gridDim.x * blockDim.x) {
    f32x4 v = *(const f32x4*)(in + i * 4);
    bf16* o = xb + i * 4;
    o[0] = __float2bfloat16(v[0]); o[1] = __float2bfloat16(v[1]);
    o[2] = __float2bfloat16(v[2]); o[3] = __float2bfloat16(v[3]);
  }
}

// merged per-layer weight repack (one launch): 21504 blocks x 256
#define SEG 262144
__global__ void repack_layer_k(const float* __restrict__ wqkv, const float* __restrict__ wout,
                               const float* __restrict__ wgate, const float* __restrict__ wff1,
                               const float* __restrict__ wff2,
                               bf16* __restrict__ q, bf16* __restrict__ o, bf16* __restrict__ g,
                               bf16* __restrict__ f1, bf16* __restrict__ f2) {
  int idx = blockIdx.x * 256 + threadIdx.x;
  if (idx < 9 * SEG) {                   // w_qkv [3][512][512][3] (j,o,i,t) -> [t][j][o][i]
    int ii = idx & 511; int r = idx >> 9;
    int oo = r & 511; r >>= 9;
    int j = r % 3, t = r / 3;
    q[idx] = __float2bfloat16(wqkv[(((size_t)j * 512 + oo) * 512 + ii) * 3 + t]);
  } else if (idx < 12 * SEG) {           // w_out [512][512][3] (o,i,t) -> [t][o][i]
    int k = idx - 9 * SEG;
    int ii = k & 511; int r = k >> 9;
    int oo = r & 511; int t = r >> 9;
    o[k] = __float2bfloat16(wout[((size_t)oo * 512 + ii) * 3 + t]);
  } else if (idx < 13 * SEG) {
    int k = idx - 12 * SEG;
    g[k] = __float2bfloat16(wgate[k]);
  } else if (idx < 17 * SEG) {
    int k = idx - 13 * SEG;
    f1[k] = __float2bfloat16(wff1[k]);
  } else {
    int k = idx - 17 * SEG;
    f2[k] = __float2bfloat16(wff2[k]);
  }
}

// ---------------- GEMM: C[M,N] = sum_t A_shift(t)[M,K] * W_t[N,K] ----------------
// BM=256, BN=256, BK=64, 8 waves (2M x 4N), 16x16x32 MFMA, 3 fine phases/K-tile.
// SINGLE 64KB LDS buffer; occupancy comes from NATURAL limits (LDS 160/64 -> 2
// blocks/CU; VGPR ~116 <= 128 -> 16 waves/CU). launch_bounds min-waves stays 2
// so the allocator is NOT register-squeezed (round-10 lesson: (512,4) forced
// 64 VGPR -> accumulator spill -> 2GB scratch traffic, 7x slowdown).
// Ledger (per-thread queue, verified): prologue a0,b0,b1,a1 of tile 0;
// P0 vmcnt(t==0?4:2) then stage a1(t); P1 vmcnt(2) then stage a0,b0(t+1);
// P2 vmcnt(pre?4:0) then stage b1(t+1). Uniform 2-phase issue->consume depth.
enum { E_SIG = 0, E_BIAS = 1, E_OUT = 2, E_RELU = 3, E_FF2 = 4 };

#define ABUF 16384   // 256*64 bf16 elements (A region)
#define BUFE 32768   // A + B regions (single buffer, 64KB)

template<int TAPS, int EPI, int KK>
__global__ __launch_bounds__(512, 2)
void gemm_k(const bf16* __restrict__ A, const bf16* __restrict__ W,
            const float* __restrict__ bias,
            bf16* __restrict__ Cb,
            const bf16* __restrict__ gate, const int* __restrict__ mask,
            const bf16* __restrict__ xres, const bf16* __restrict__ zbuf,
            int M, int N)
{
  constexpr int KT = KK / 64;        // K-tiles per tap
  constexpr int NT = TAPS * KT;      // virtual K-tiles
  __shared__ bf16 lds[BUFE];         // 65536 B -> 2 blocks/CU by LDS limit

  const int tid  = threadIdx.x;
  const int lane = tid & 63;
  const int w    = tid >> 6;         // 0..7
  const int wr   = w >> 2;           // 0..1 (M)
  const int wc   = w & 3;            // 0..3 (N)
  const int frow = lane & 15;
  const int kq   = lane >> 4;        // 0..3

  // T1: bijective XCD swizzle (nwg % 8 == 0 for all instantiations)
  const int nwg = gridDim.x * gridDim.y;
  const int wg  = blockIdx.y * gridDim.x + blockIdx.x;
  const int q8  = nwg >> 3;
  const int swz = (wg & 7) * q8 + (wg >> 3);
  const int row0 = (swz / gridDim.x) * 256;
  const int n0   = (swz % gridDim.x) * 256;

  // ---- precomputed staging state ----
  const int gA   = tid & 7;
  const bf16* aptr[4];
  int oobt[4];                        // tap index that must read zbuf (3 = none)
#pragma unroll
  for (int i = 0; i < 4; ++i) {
    int row  = i * 64 + (tid >> 3);
    int grow = row0 + row;
    int gswA = (gA ^ (row & 7)) * 8;
    if (TAPS == 3) {
      int l = grow & (SEQ - 1);
      oobt[i] = (l == 0) ? 0 : ((l == SEQ - 1) ? 2 : 3);
      aptr[i] = A + (size_t)(grow - 1) * KK + gswA;   // shift = -1 start
    } else {
      oobt[i] = 3;
      aptr[i] = A + (size_t)grow * KK + gswA;
    }
  }
  const int uB = tid >> 3;
  const bf16* bptr[4];
  int dstB[4];
#pragma unroll
  for (int j = 0; j < 4; ++j) {
    int row = (j >> 1) * 128 + (j & 1) * 32 + (uB & 31) + (uB >> 5) * 64;
    int gsw = (gA ^ (row & 7)) * 8;
    bptr[j] = W + (size_t)(n0 + row) * KK + gsw;
    dstB[j] = ABUF + row * 64 + gA * 8;
  }
  const size_t tapSkipB = (size_t)(N - 1) * KK;   // jump between taps for B

  auto stageA = [&](int v, int i) {
    const bf16* s = aptr[i] + (size_t)v * 64;
    if (TAPS == 3) {
      int tap = v >> 3;
      if (tap == oobt[i]) s = zbuf;
    }
    gload_lds16(s, lds + i * 4096 + tid * 8);
  };
  auto stageB = [&](int v, int j) {
    const bf16* s = bptr[j] + (size_t)v * 64;
    if (TAPS == 3) s += (size_t)(v >> 3) * tapSkipB;
    gload_lds16(s, lds + dstB[j]);
  };

  f32x4 acc[8][4] = {};

  // prologue: tile 0, EXACT order a0(A0,A2), b0(B0,B2), b1(B1,B3), a1(A1,A3)
  stageA(0, 0); stageA(0, 2); stageB(0, 0); stageB(0, 2);
  stageB(0, 1); stageB(0, 3); stageA(0, 1); stageA(0, 3);

#pragma unroll 1
  for (int t = 0; t < NT; ++t) {
    const bf16* Ab = lds;
    const bf16* Bb = lds + ABUF;
    const bool pre = (t + 1 < NT);

    auto ldA = [&](int mi, int ks) -> s16x8 {   // mi 0..7
      int row = wr * 128 + mi * 16 + frow;
      int kg  = ks * 4 + kq;
      return *(const s16x8*)&Ab[row * 64 + ((kg ^ (row & 7)) * 8)];
    };
    auto ldB = [&](int nj, int ks) -> s16x8 {   // nj 0..3
      int row = wc * 64 + nj * 16 + frow;
      int kg  = ks * 4 + kq;
      return *(const s16x8*)&Bb[row * 64 + ((kg ^ (row & 7)) * 8)];
    };

    s16x8 a0[4][2], a1[4][2], b0[2][2], b1[2][2];

    // ---- phase 0: reads A{0,2}+B{0,2} regions of t ----
    if (t == 0) asm volatile("s_waitcnt vmcnt(4)" ::: "memory");
    else        asm volatile("s_waitcnt vmcnt(2)" ::: "memory");
    __builtin_amdgcn_s_barrier();
    asm volatile("" ::: "memory");
    if (t > 0) { stageA(t, 1); stageA(t, 3); }   // a1(t): region freed at P2 of t-1
#pragma unroll
    for (int mi = 0; mi < 4; ++mi)
#pragma unroll
      for (int ks = 0; ks < 2; ++ks) a0[mi][ks] = ldA(mi, ks);
#pragma unroll
    for (int nj = 0; nj < 2; ++nj)
#pragma unroll
      for (int ks = 0; ks < 2; ++ks) b0[nj][ks] = ldB(nj, ks);
    __builtin_amdgcn_s_setprio(1);
#pragma unroll
    for (int mi = 0; mi < 4; ++mi)
#pragma unroll
      for (int nj = 0; nj < 2; ++nj) {
        acc[mi][nj] = __builtin_amdgcn_mfma_f32_16x16x32_bf16(a0[mi][0], b0[nj][0], acc[mi][nj], 0, 0, 0);
        acc[mi][nj] = __builtin_amdgcn_mfma_f32_16x16x32_bf16(a0[mi][1], b0[nj][1], acc[mi][nj], 0, 0, 0);
      }
    __builtin_amdgcn_s_setprio(0);

    // ---- phase 1: reads B{1,3} region of t ----
    asm volatile("s_waitcnt vmcnt(2)" ::: "memory");
    __builtin_amdgcn_s_barrier();
    asm volatile("" ::: "memory");
    if (pre) { stageA(t + 1, 0); stageA(t + 1, 2); stageB(t + 1, 0); stageB(t + 1, 2); }
#pragma unroll
    for (int nj = 0; nj < 2; ++nj)
#pragma unroll
      for (int ks = 0; ks < 2; ++ks) b1[nj][ks] = ldB(2 + nj, ks);
    __builtin_amdgcn_s_setprio(1);
#pragma unroll
    for (int mi = 0; mi < 4; ++mi)
#pragma unroll
      for (int nj = 0; nj < 2; ++nj) {
        acc[mi][2 + nj] = __builtin_amdgcn_mfma_f32_16x16x32_bf16(a0[mi][0], b1[nj][0], acc[mi][2 + nj], 0, 0, 0);
        acc[mi][2 + nj] = __builtin_amdgcn_mfma_f32_16x16x32_bf16(a0[mi][1], b1[nj][1], acc[mi][2 + nj], 0, 0, 0);
      }
    __builtin_amdgcn_s_setprio(0);

    // ---- phase 2: reads A{1,3} region of t ----
    if (pre) asm volatile("s_waitcnt vmcnt(4)" ::: "memory");
    else     asm volatile("s_waitcnt vmcnt(0)" ::: "memory");
    __builtin_amdgcn_s_barrier();
    asm volatile("" ::: "memory");
    if (pre) { stageB(t + 1, 1); stageB(t + 1, 3); }
#pragma unroll
    for (int mi = 0; mi < 4; ++mi)
#pragma unroll
      for (int ks = 0; ks < 2; ++ks) a1[mi][ks] = ldA(4 + mi, ks);
    __builtin_amdgcn_s_setprio(1);
#pragma unroll
    for (int mi = 0; mi < 4; ++mi)
#pragma unroll
      for (int nj = 0; nj < 2; ++nj) {
        acc[4 + mi][nj] = __builtin_amdgcn_mfma_f32_16x16x32_bf16(a1[mi][0], b0[nj][0], acc[4 + mi][nj], 0, 0, 0);
        acc[4 + mi][nj] = __builtin_amdgcn_mfma_f32_16x16x32_bf16(a1[mi][1], b0[nj][1], acc[4 + mi][nj], 0, 0, 0);
      }
#pragma unroll
    for (int mi = 0; mi < 4; ++mi)
#pragma unroll
      for (int nj = 0; nj < 2; ++nj) {
        acc[4 + mi][2 + nj] = __builtin_amdgcn_mfma_f32_16x16x32_bf16(a1[mi][0], b1[nj][0], acc[4 + mi][2 + nj], 0, 0, 0);
        acc[4 + mi][2 + nj] = __builtin_amdgcn_mfma_f32_16x16x32_bf16(a1[mi][1], b1[nj][1], acc[4 + mi][2 + nj], 0, 0, 0);
      }
    __builtin_amdgcn_s_setprio(0);
  }

  // epilogue: C/D layout col=lane&15, row=(lane>>4)*4+j (m89-verified)
#pragma unroll
  for (int mi = 0; mi < 8; ++mi) {
    int rowb = row0 + wr * 128 + mi * 16 + kq * 4;
#pragma unroll
    for (int nj = 0; nj < 4; ++nj) {
      int col = n0 + wc * 64 + nj * 16 + frow;
      float bval = bias[col];
#pragma unroll
      for (int j = 0; j < 4; ++j) {
        int rr = rowb + j;
        float v = acc[mi][nj][j] + bval;
        size_t idx = (size_t)rr * N + col;
        if (EPI == E_SIG) {
          Cb[idx] = __float2bfloat16(1.f / (1.f + __expf(-v)));
        } else if (EPI == E_BIAS) {
          Cb[idx] = __float2bfloat16(v);
        } else if (EPI == E_RELU) {
          Cb[idx] = __float2bfloat16(fmaxf(v, 0.f));
        } else if (EPI == E_OUT) {
          float gf = __bfloat162float(gate[idx]);
          float mf = (float)mask[rr];
          float rv = __bfloat162float(xres[idx]);
          Cb[idx] = __float2bfloat16(rv + v * gf * mf);
        } else if (EPI == E_FF2) {
          float mf = (float)mask[rr];
          float rv = __bfloat162float(xres[idx]);
          Cb[idx] = __float2bfloat16(rv + v * mf);
        }
      }
    }
  }
}

// ---------------- column max over L (two stage) ----------------
__global__ void colmax_partial_k(const bf16* __restrict__ k, const bf16* __restrict__ v,
                                 float* __restrict__ pk, float* __restrict__ pv) {
  int b  = blockIdx.x >> 1;
  int d  = ((blockIdx.x & 1) << 8) + threadIdx.x;
  int lc = blockIdx.y;
  const int CH = SEQ / 16;
  size_t base = ((size_t)b * SEQ + (size_t)lc * CH) * 1536 + d;
  float mk = -1e30f, mv = -1e30f;
  for (int l = 0; l < CH; ++l) {
    mk = fmaxf(mk, __bfloat162float(k[base]));
    mv = fmaxf(mv, __bfloat162float(v[base]));
    base += 1536;
  }
  size_t pidx = ((size_t)lc * BATCH + b) * DMODEL + d;
  pk[pidx] = mk; pv[pidx] = mv;
}

__global__ void colmax_final_k(const float* __restrict__ pk, const float* __restrict__ pv,
                               float* __restrict__ kg, float* __restrict__ vg) {
  int b = blockIdx.x >> 1;
  int d = ((blockIdx.x & 1) << 8) + threadIdx.x;
  float mk = -1e30f, mv = -1e30f;
  for (int lc = 0; lc < 16; ++lc) {
    size_t pidx = ((size_t)lc * BATCH + b) * DMODEL + d;
    mk = fmaxf(mk, pk[pidx]);
    mv = fmaxf(mv, pv[pidx]);
  }
  kg[(size_t)b * DMODEL + d] = mk;
  vg[(size_t)b * DMODEL + d] = mv;
}

// ---------------- 2-way softmax attention (wave per token, 16B/lane) --------
__global__ void attn_k(const bf16* __restrict__ qkv, const float* __restrict__ kg,
                       const float* __restrict__ vg, bf16* __restrict__ o) {
  int wid = threadIdx.x >> 6, lane = threadIdx.x & 63;
  int m = blockIdx.x * 4 + wid;
  int b = m >> 11;   // SEQ = 2048
  size_t base3 = (size_t)m * 1536 + lane * 8;
  const float scale = 0.04419417382415922f;  // 1/sqrt(512)
  s16x8 qv = *(const s16x8*)(qkv + base3);
  s16x8 kv = *(const s16x8*)(qkv + base3 + 512);
  s16x8 vv = *(const s16x8*)(qkv + base3 + 1024);
  size_t gbase = ((size_t)b << 9) + lane * 8;
  f32x4 kg0 = *(const f32x4*)(kg + gbase), kg1 = *(const f32x4*)(kg + gbase + 4);
  f32x4 vg0 = *(const f32x4*)(vg + gbase), vg1 = *(const f32x4*)(vg + gbase + 4);
  float qf[8], kf[8], vf[8], kgf[8], vgf[8];
#pragma unroll
  for (int j = 0; j < 8; ++j) {
    qf[j] = b2f(qv[j]);
    kf[j] = b2f(kv[j]);
    vf[j] = b2f(vv[j]);
    kgf[j] = (j < 4) ? kg0[j] : kg1[j - 4];
    vgf[j] = (j < 4) ? vg0[j] : vg1[j - 4];
  }
  float sl = 0.f, sg = 0.f;
#pragma unroll
  for (int j = 0; j < 8; ++j) { sl += qf[j] * kf[j]; sg += qf[j] * kgf[j]; }
  // segmented reduce over the 8-lane head group (head = lane>>3)
#pragma unroll
  for (int off = 4; off; off >>= 1) {
    sl += __shfl_xor(sl, off);
    sg += __shfl_xor(sg, off);
  }
  sl *= scale; sg *= scale;
  float mx = fmaxf(sl, sg);
  float e0 = __expf(sl - mx), e1 = __expf(sg - mx);
  float inv = 1.f / (e0 + e1);
  s16x8 ov;
#pragma unroll
  for (int j = 0; j < 8; ++j)
    ov[j] = f2b((e0 * vf[j] + e1 * vgf[j]) * inv);
  *(s16x8*)(o + (size_t)m * DMODEL + lane * 8) = ov;
}

// ---------------- residual'd input -> LayerNorm (wave per row) ----------------
template<bool FINAL>
__global__ void ln_k(const bf16* __restrict__ r, const float* __restrict__ g,
                     const float* __restrict__ b, bf16* __restrict__ xb,
                     float* __restrict__ xo) {
  int wid = threadIdx.x >> 6, lane = threadIdx.x & 63;
  int row = blockIdx.x * 4 + wid;
  size_t base = (size_t)row * DMODEL + lane * 8;
  s16x8 rv = *(const s16x8*)(r + base);
  float f[8];
  float s = 0.f, ss = 0.f;
#pragma unroll
  for (int j = 0; j < 8; ++j) {
    f[j] = b2f(rv[j]);
    s += f[j]; ss += f[j] * f[j];
  }
#pragma unroll
  for (int off = 32; off; off >>= 1) {
    s  += __shfl_xor(s, off);
    ss += __shfl_xor(ss, off);
  }
  float mean = s * (1.f / (float)DMODEL);
  float var  = ss * (1.f / (float)DMODEL) - mean * mean;
  float inv  = rsqrtf(var + 1e-5f);
  int c = lane * 8;
  f32x4 g0 = *(const f32x4*)(g + c), g1 = *(const f32x4*)(g + c + 4);
  f32x4 b0 = *(const f32x4*)(b + c), b1 = *(const f32x4*)(b + c + 4);
  float y[8];
#pragma unroll
  for (int j = 0; j < 8; ++j) {
    float gj = (j < 4) ? g0[j] : g1[j - 4];
    float bj = (j < 4) ? b0[j] : b1[j - 4];
    y[j] = (f[j] - mean) * inv * gj + bj;
  }
  s16x8 yb;
#pragma unroll
  for (int j = 0; j < 8; ++j) yb[j] = f2b(y[j]);
  *(s16x8*)(xb + base) = yb;
  if (FINAL) {
    f32x4 o0, o1;
#pragma unroll
    for (int j = 0; j < 4; ++j) { o0[j] = y[j]; o1[j] = y[4 + j]; }
    *(f32x4*)(xo + base) = o0;
    *(f32x4*)(xo + base + 4) = o1;
  }
}

// ---------------- launch ----------------
extern "C" void kernel_launch(void* const* d_in, const int* in_sizes, int n_in,
                              void* d_out, int out_size, void* d_ws, size_t ws_size,
                              hipStream_t stream) {
  (void)in_sizes; (void)n_in; (void)out_size;
  const float* x      = (const float*)d_in[0];
  const int*   xmask  = (const int*)d_in[1];
  const float* w_qkv  = (const float*)d_in[2];
  const float* b_qkv  = (const float*)d_in[3];
  const float* w_gate = (const float*)d_in[4];
  const float* b_gate = (const float*)d_in[5];
  const float* w_out  = (const float*)d_in[6];
  const float* b_out  = (const float*)d_in[7];
  const float* ln1_g  = (const float*)d_in[8];
  const float* ln1_b  = (const float*)d_in[9];
  const float* w_ff1  = (const float*)d_in[10];
  const float* b_ff1  = (const float*)d_in[11];
  const float* w_ff2  = (const float*)d_in[12];
  const float* b_ff2  = (const float*)d_in[13];
  const float* ln2_g  = (const float*)d_in[14];
  const float* ln2_b  = (const float*)d_in[15];
  float* xo = (float*)d_out;

  char* ws = (char*)d_ws;
  size_t off = 0;
  auto alloc = [&](size_t bytes) {
    char* p = ws + off;
    off += (bytes + 255) & ~(size_t)255;
    return p;
  };
  // xb: bf16 copy of current x (always live)
  bf16* xb = (bf16*)alloc((size_t)MROWS * DMODEL * 2);
  // R2 shared region:
  //  attn phase: [qkvb 100.7MB | gateb 33.5MB]
  //  post-attn:  resb (bf16 residual, 33.5MB) overlays dead qkvb[0..]
  //  FFN phase:  hb (134.2MB) overlays everything (resb+gateb dead by then)
  char* R2 = alloc((size_t)MROWS * FFDIM * 2);              // 134,217,728 B
  bf16* qkvb  = (bf16*)R2;
  bf16* gateb = (bf16*)(R2 + (size_t)MROWS * 1536 * 2);
  bf16* resb  = (bf16*)R2;                                  // E_OUT out, ln1 in
  bf16* hb    = (bf16*)R2;                                  // FFN hidden
  bf16* ob    = (bf16*)alloc((size_t)MROWS * DMODEL * 2);   // attn out; later E_FF2 out
  float* kg   = (float*)alloc((size_t)BATCH * DMODEL * 4);
  float* vg   = (float*)alloc((size_t)BATCH * DMODEL * 4);
  float* pk   = (float*)alloc((size_t)16 * BATCH * DMODEL * 4);
  float* pv   = (float*)alloc((size_t)16 * BATCH * DMODEL * 4);
  bf16* zbuf  = (bf16*)alloc(256);
  // per-layer repacked weights (overwritten each layer)
  bf16* wq  = (bf16*)alloc((size_t)9 * DMODEL * DMODEL * 2);
  bf16* wg  = (bf16*)alloc((size_t)DMODEL * DMODEL * 2);
  bf16* wo  = (bf16*)alloc((size_t)3 * DMODEL * DMODEL * 2);
  bf16* wf1 = (bf16*)alloc((size_t)FFDIM * DMODEL * 2);
  bf16* wf2 = (bf16*)alloc((size_t)DMODEL * FFDIM * 2);

  // tripwire: if ws is too small, do nothing -> clean absmax fail (not a crash)
  if (off > ws_size) return;

  hipMemsetAsync(zbuf, 0, 256, stream);
  x_init_k<<<2048, 256, 0, stream>>>(x, xb, (size_t)MROWS * DMODEL / 4);

  dim3 gN512(512 / 256, MROWS / 256);    // (2, 128)  -> 256 blocks
  dim3 gN1536(1536 / 256, MROWS / 256);  // (6, 128)  -> 768 blocks
  dim3 gN2048(2048 / 256, MROWS / 256);  // (8, 128)  -> 1024 blocks

  for (int i = 0; i < NLAYER; ++i) {
    repack_layer_k<<<21 * SEG / 256, 256, 0, stream>>>(
        w_qkv + (size_t)i * 3 * DMODEL * DMODEL * 3,
        w_out + (size_t)i * DMODEL * DMODEL * 3,
        w_gate + (size_t)i * DMODEL * DMODEL,
        w_ff1 + (size_t)i * FFDIM * DMODEL,
        w_ff2 + (size_t)i * DMODEL * FFDIM,
        wq, wo, wg, wf1, wf2);

    // gate = sigmoid(x @ w_gate^T + b_gate)
    gemm_k<1, E_SIG, 512><<<gN512, 512, 0, stream>>>(
        xb, wg, b_gate + (size_t)i * DMODEL, gateb,
        nullptr, nullptr, nullptr, zbuf, MROWS, DMODEL);
    // qkv = conv1d3(x) fused over q/k/v, N = 1536
    gemm_k<3, E_BIAS, 512><<<gN1536, 512, 0, stream>>>(
        xb, wq, b_qkv + (size_t)i * 3 * DMODEL, qkvb,
        nullptr, nullptr, nullptr, zbuf, MROWS, 1536);
    // k_g, v_g global max over L
    colmax_partial_k<<<dim3(32, 16), 256, 0, stream>>>(qkvb + 512, qkvb + 1024, pk, pv);
    colmax_final_k<<<32, 256, 0, stream>>>(pk, pv, kg, vg);
    // 2-way softmax attention
    attn_k<<<MROWS / 4, 256, 0, stream>>>(qkvb, kg, vg, ob);
    // resb = x + conv1d3(o) * gate * mask   (bf16 residual)
    gemm_k<3, E_OUT, 512><<<gN512, 512, 0, stream>>>(
        ob, wo, b_out + (size_t)i * DMODEL, resb,
        gateb, xmask, xb, zbuf, MROWS, DMODEL);
    // x = LN(resb)
    ln_k<false><<<MROWS / 4, 256, 0, stream>>>(resb, ln1_g + (size_t)i * DMODEL,
                                               ln1_b + (size_t)i * DMODEL, xb, nullptr);
    // h = relu(x @ w_ff1^T + b_ff1)
    gemm_k<1, E_RELU, 512><<<gN2048, 512, 0, stream>>>(
        xb, wf1, b_ff1 + (size_t)i * FFDIM, hb,
        nullptr, nullptr, nullptr, zbuf, MROWS, FFDIM);
    // ob = x + (h @ w_ff2^T + b_ff2) * mask   (bf16 residual)
    gemm_k<1, E_FF2, 2048><<<gN512, 512, 0, stream>>>(
        hb, wf2, b_ff2 + (size_t)i * DMODEL, ob,
        nullptr, xmask, xb, zbuf, MROWS, DMODEL);
    // x = LN(ob); final layer also writes f32 output
    if (i == NLAYER - 1)
      ln_k<true><<<MROWS / 4, 256, 0, stream>>>(ob, ln2_g + (size_t)i * DMODEL,
                                                ln2_b + (size_t)i * DMODEL, xb, xo);
    else
      ln_k<false><<<MROWS / 4, 256, 0, stream>>>(ob, ln2_g + (size_t)i * DMODEL,
                                                 ln2_b + (size_t)i * DMODEL, xb, nullptr);
  }
}